// Round 1
// baseline (221.447 us; speedup 1.0000x reference)
//
#include <hip/hip_runtime.h>

// Problem constants (from reference)
#define Bq 2
#define Nn 6
#define Dd 48
#define Hh 28
#define Ww 60
#define Cc 64
#define Xd 200
#define Yd 200
#define NP (Nn*Dd*Hh*Ww)      // 483840 points per batch
#define TOTP (Bq*NP)          // 967680 total points
#define NVOX (Xd*Yd)          // 40000 voxels per batch (Z=1)

// ---------------------------------------------------------------------------
// Scatter: one wave (64 lanes) per frustum point; lane l owns channel l.
// Accumulate into channel-contiguous scratch ws[B][X][Y][C] so each point's
// 64 atomic adds hit 4 consecutive cache lines.
// ---------------------------------------------------------------------------
__global__ __launch_bounds__(256) void fiery_scatter(
    const float* __restrict__ x, const float* __restrict__ geom,
    float* __restrict__ ws)
{
    int wid  = blockIdx.x * 4 + (threadIdx.x >> 6);   // point id
    int lane = threadIdx.x & 63;                      // channel
    if (wid >= TOTP) return;

    // voxelize (must match numpy astype(int32): truncate toward zero)
    long gb = (long)wid * 3;
    float gx = geom[gb + 0];
    float gy = geom[gb + 1];
    float gz = geom[gb + 2];
    int vx = (int)((gx + 50.0f) / 0.5f);
    int vy = (int)((gy + 50.0f) / 0.5f);
    int vz = (int)((gz + 10.0f) / 20.0f);
    bool valid = (vx >= 0) && (vx < Xd) && (vy >= 0) && (vy < Yd) && (vz == 0);
    if (!valid) return;                                // wave-uniform

    int b = (wid >= NP) ? 1 : 0;
    float v = x[(long)wid * Cc + lane];                // coalesced 256B
    long dst = ((long)(b * NVOX + vx * Yd + vy)) * Cc + lane;
    atomicAdd(&ws[dst], v);
}

// Fallback (ws too small): scatter straight into out[B][C][X][Y].
__global__ __launch_bounds__(256) void fiery_scatter_direct(
    const float* __restrict__ x, const float* __restrict__ geom,
    float* __restrict__ out)
{
    int wid  = blockIdx.x * 4 + (threadIdx.x >> 6);
    int lane = threadIdx.x & 63;
    if (wid >= TOTP) return;
    long gb = (long)wid * 3;
    float gx = geom[gb + 0];
    float gy = geom[gb + 1];
    float gz = geom[gb + 2];
    int vx = (int)((gx + 50.0f) / 0.5f);
    int vy = (int)((gy + 50.0f) / 0.5f);
    int vz = (int)((gz + 10.0f) / 20.0f);
    bool valid = (vx >= 0) && (vx < Xd) && (vy >= 0) && (vy < Yd) && (vz == 0);
    if (!valid) return;
    int b = (wid >= NP) ? 1 : 0;
    float v = x[(long)wid * Cc + lane];
    long dst = ((long)(b * Cc + lane)) * NVOX + (vx * Yd + vy);
    atomicAdd(&out[dst], v);
}

// ---------------------------------------------------------------------------
// Transpose ws[B][XY][C] -> out[B][C][XY], LDS-tiled (64 rows x 64 channels).
// Fully overwrites out.
// ---------------------------------------------------------------------------
__global__ __launch_bounds__(256) void fiery_transpose(
    const float* __restrict__ ws, float* __restrict__ out)
{
    __shared__ float tile[64][65];
    int t  = blockIdx.x;            // 0 .. 2*625-1
    int b  = t / 625;
    int r0 = (t % 625) * 64;        // row tile base within [0,40000)
    int tid = threadIdx.x;

    const float* src = ws + ((long)b * NVOX + r0) * Cc;
    int c  = tid & 63;
    int rr = tid >> 6;              // 0..3
    #pragma unroll
    for (int s = 0; s < 16; ++s) {
        int r = rr + s * 4;
        tile[r][c] = src[(long)r * Cc + c];      // coalesced read
    }
    __syncthreads();

    float* dst = out + (long)b * Cc * NVOX + r0;
    int r2 = tid & 63;
    int c2 = tid >> 6;              // 0..3
    #pragma unroll
    for (int s = 0; s < 16; ++s) {
        int cc = c2 + s * 4;
        dst[(long)cc * NVOX + r2] = tile[r2][cc]; // coalesced write
    }
}

extern "C" void kernel_launch(void* const* d_in, const int* in_sizes, int n_in,
                              void* d_out, int out_size, void* d_ws, size_t ws_size,
                              hipStream_t stream)
{
    const float* x    = (const float*)d_in[0];
    const float* geom = (const float*)d_in[1];
    float* out = (float*)d_out;

    size_t need = (size_t)Bq * NVOX * Cc * sizeof(float);   // 10.24 MB
    int blocks = TOTP / 4;                                  // 4 waves/block, exact

    if (ws_size >= need) {
        float* ws = (float*)d_ws;
        hipMemsetAsync(ws, 0, need, stream);
        fiery_scatter<<<blocks, 256, 0, stream>>>(x, geom, ws);
        fiery_transpose<<<Bq * (NVOX / 64), 256, 0, stream>>>(ws, out);
    } else {
        hipMemsetAsync(out, 0, (size_t)out_size * sizeof(float), stream);
        fiery_scatter_direct<<<blocks, 256, 0, stream>>>(x, geom, out);
    }
}

// Round 2
// 202.634 us; speedup vs baseline: 1.0928x; 1.0928x over previous
//
#include <hip/hip_runtime.h>

#define Bq 2
#define Nn 6
#define Dd 48
#define Hh 28
#define Ww 60
#define Cc 64
#define Xd 200
#define Yd 200
#define NP (Nn*Dd*Hh*Ww)      // 483840 points per batch
#define TOTP (Bq*NP)          // 967680 total points
#define NVOX (Xd*Yd)          // 40000 voxels per batch (Z=1)
#define NSEG (Bq*NVOX)        // 80000 segments
#define NB1  79               // ceil(NSEG/1024)

// ---------------------------------------------------------------------------
// Phase A: voxelize each point, store segment id (-1 invalid), histogram count
// ---------------------------------------------------------------------------
__global__ __launch_bounds__(256) void phase_a(
    const float* __restrict__ geom, int* __restrict__ rank, int* __restrict__ cnt)
{
    int p = blockIdx.x * 256 + threadIdx.x;
    if (p >= TOTP) return;
    float gx = geom[(long)p*3 + 0];
    float gy = geom[(long)p*3 + 1];
    float gz = geom[(long)p*3 + 2];
    // must match numpy astype(int32): truncate toward zero, f32 arithmetic
    int vx = (int)((gx + 50.0f) / 0.5f);
    int vy = (int)((gy + 50.0f) / 0.5f);
    int vz = (int)((gz + 10.0f) / 20.0f);
    int seg = -1;
    if (vx >= 0 && vx < Xd && vy >= 0 && vy < Yd && vz == 0) {
        int b = (p >= NP) ? 1 : 0;
        seg = b * NVOX + vx * Yd + vy;
        atomicAdd(&cnt[seg], 1);
    }
    rank[p] = seg;
}

// ---------------------------------------------------------------------------
// Scan P1: per-1024-block exclusive scan of cnt -> start, block totals -> bsum
// ---------------------------------------------------------------------------
__global__ __launch_bounds__(1024) void scan_p1(
    const int* __restrict__ cnt, int* __restrict__ start, int* __restrict__ bsum)
{
    __shared__ int sh[1024];
    int tid = threadIdx.x;
    int i = blockIdx.x * 1024 + tid;
    int v = (i < NSEG) ? cnt[i] : 0;
    sh[tid] = v;
    __syncthreads();
    for (int off = 1; off < 1024; off <<= 1) {
        int t = (tid >= off) ? sh[tid - off] : 0;
        __syncthreads();
        sh[tid] += t;
        __syncthreads();
    }
    if (i < NSEG) start[i] = sh[tid] - v;          // exclusive
    if (tid == 1023) bsum[blockIdx.x] = sh[1023];  // block total
}

// Scan P2: exclusive scan of the NB1 block totals (single block)
__global__ __launch_bounds__(128) void scan_p2(int* __restrict__ bsum)
{
    __shared__ int sh[128];
    int tid = threadIdx.x;
    int v = (tid < NB1) ? bsum[tid] : 0;
    sh[tid] = v;
    __syncthreads();
    for (int off = 1; off < 128; off <<= 1) {
        int t = (tid >= off) ? sh[tid - off] : 0;
        __syncthreads();
        sh[tid] += t;
        __syncthreads();
    }
    if (tid < NB1) bsum[tid] = sh[tid] - v;        // exclusive
}

// Scan P3: add block offsets
__global__ __launch_bounds__(1024) void scan_p3(
    int* __restrict__ start, const int* __restrict__ bsum)
{
    int i = blockIdx.x * 1024 + threadIdx.x;
    if (i < NSEG) start[i] += bsum[blockIdx.x];
}

// ---------------------------------------------------------------------------
// Phase C: scatter point ids into segment-ordered list; start[] becomes end[]
// ---------------------------------------------------------------------------
__global__ __launch_bounds__(256) void phase_c(
    const int* __restrict__ rank, int* __restrict__ start, int* __restrict__ order)
{
    int p = blockIdx.x * 256 + threadIdx.x;
    if (p >= TOTP) return;
    int seg = rank[p];
    if (seg < 0) return;
    int pos = atomicAdd(&start[seg], 1);
    order[pos] = p;
}

// ---------------------------------------------------------------------------
// Phase D: one wave per 16 voxels, 64 voxels per block; sum features in regs,
// LDS-transpose the 64x64 tile, write out[b][c][xy] coalesced. No atomics.
// endp[] is the mutated start[] (now segment end pointers).
// ---------------------------------------------------------------------------
__global__ __launch_bounds__(256) void phase_d(
    const int* __restrict__ endp, const int* __restrict__ order,
    const float* __restrict__ x, float* __restrict__ out)
{
    __shared__ float tile[64][65];
    int blk  = blockIdx.x;                 // 0 .. 1249
    int b    = blk / (NVOX/64);            // 625 blocks per batch
    int xy0  = (blk % (NVOX/64)) * 64;
    int wv   = threadIdx.x >> 6;
    int lane = threadIdx.x & 63;
    int seg0 = b * NVOX + xy0 + wv * 16;

    // lane j<17 loads boundary end[seg0-1+j]; e[v]=begin of voxel v, e[v+1]=end
    int e = 0;
    if (lane < 17) {
        int idx = seg0 - 1 + lane;
        e = (idx >= 0) ? endp[idx] : 0;
    }

    for (int v = 0; v < 16; ++v) {
        int begin = __shfl(e, v);
        int endv  = __shfl(e, v + 1);
        float sum = 0.0f;
        for (int base = begin; base < endv; base += 64) {
            int cnt = endv - base; if (cnt > 64) cnt = 64;
            int pid = 0;
            if (lane < cnt) pid = order[base + lane];
            for (int t = 0; t < cnt; ++t) {
                int p = __shfl(pid, t);
                sum += x[(long)p * Cc + lane];
            }
        }
        tile[wv * 16 + v][lane] = sum;
    }
    __syncthreads();

    float* dst = out + (long)b * Cc * NVOX + xy0;
    #pragma unroll
    for (int s = 0; s < 16; ++s) {
        int c = wv + s * 4;
        dst[(long)c * NVOX + lane] = tile[lane][c];
    }
}

// ---------------------------------------------------------------------------
// Fallback (r1 atomic path) if ws is unexpectedly small
// ---------------------------------------------------------------------------
__global__ __launch_bounds__(256) void fiery_scatter_direct(
    const float* __restrict__ x, const float* __restrict__ geom,
    float* __restrict__ out)
{
    int wid  = blockIdx.x * 4 + (threadIdx.x >> 6);
    int lane = threadIdx.x & 63;
    if (wid >= TOTP) return;
    long gb = (long)wid * 3;
    float gx = geom[gb+0], gy = geom[gb+1], gz = geom[gb+2];
    int vx = (int)((gx + 50.0f) / 0.5f);
    int vy = (int)((gy + 50.0f) / 0.5f);
    int vz = (int)((gz + 10.0f) / 20.0f);
    if (!(vx >= 0 && vx < Xd && vy >= 0 && vy < Yd && vz == 0)) return;
    int b = (wid >= NP) ? 1 : 0;
    float vv = x[(long)wid * Cc + lane];
    long dst = ((long)(b * Cc + lane)) * NVOX + (vx * Yd + vy);
    atomicAdd(&out[dst], vv);
}

extern "C" void kernel_launch(void* const* d_in, const int* in_sizes, int n_in,
                              void* d_out, int out_size, void* d_ws, size_t ws_size,
                              hipStream_t stream)
{
    const float* x    = (const float*)d_in[0];
    const float* geom = (const float*)d_in[1];
    float* out = (float*)d_out;

    // ws layout: rank[TOTP] | order[TOTP] | cnt[NSEG] | start[NSEG] | bsum[128]
    size_t need = ((size_t)TOTP * 2 + (size_t)NSEG * 2 + 128) * sizeof(int);
    if (ws_size >= need) {
        int* rank  = (int*)d_ws;
        int* order = rank  + TOTP;
        int* cnt   = order + TOTP;
        int* start = cnt   + NSEG;
        int* bsum  = start + NSEG;

        hipMemsetAsync(cnt, 0, (size_t)NSEG * sizeof(int), stream);
        phase_a<<<TOTP/256, 256, 0, stream>>>(geom, rank, cnt);
        scan_p1<<<NB1, 1024, 0, stream>>>(cnt, start, bsum);
        scan_p2<<<1, 128, 0, stream>>>(bsum);
        scan_p3<<<NB1, 1024, 0, stream>>>(start, bsum);
        phase_c<<<TOTP/256, 256, 0, stream>>>(rank, start, order);
        phase_d<<<Bq*(NVOX/64), 256, 0, stream>>>(start, order, x, out);
    } else {
        hipMemsetAsync(out, 0, (size_t)out_size * sizeof(float), stream);
        fiery_scatter_direct<<<TOTP/4, 256, 0, stream>>>(x, geom, out);
    }
}

// Round 4
// 134.647 us; speedup vs baseline: 1.6446x; 1.5049x over previous
//
#include <hip/hip_runtime.h>

#define Bq 2
#define Nn 6
#define Dd 48
#define Hh 28
#define Ww 60
#define Cc 64
#define Xd 200
#define Yd 200
#define NP (Nn*Dd*Hh*Ww)      // 483840 points per batch
#define TOTP (Bq*NP)          // 967680 total points
#define NVOX (Xd*Yd)          // 40000 voxels per batch (Z=1)
#define NSEG (Bq*NVOX)        // 80000 segments
#define NB1  79               // ceil(NSEG/1024)

// ---------------------------------------------------------------------------
// Phase A: voxelize each point, store segment id (-1 invalid), histogram count
// ---------------------------------------------------------------------------
__global__ __launch_bounds__(256) void phase_a(
    const float* __restrict__ geom, int* __restrict__ rank, int* __restrict__ cnt)
{
    int p = blockIdx.x * 256 + threadIdx.x;
    if (p >= TOTP) return;
    float gx = geom[(long)p*3 + 0];
    float gy = geom[(long)p*3 + 1];
    float gz = geom[(long)p*3 + 2];
    // must match numpy astype(int32): truncate toward zero, f32 arithmetic
    int vx = (int)((gx + 50.0f) / 0.5f);
    int vy = (int)((gy + 50.0f) / 0.5f);
    int vz = (int)((gz + 10.0f) / 20.0f);
    int seg = -1;
    if (vx >= 0 && vx < Xd && vy >= 0 && vy < Yd && vz == 0) {
        int b = (p >= NP) ? 1 : 0;
        seg = b * NVOX + vx * Yd + vy;
        atomicAdd(&cnt[seg], 1);
    }
    rank[p] = seg;
}

// Scan P1: per-1024-block exclusive scan of cnt -> start, block totals -> bsum
__global__ __launch_bounds__(1024) void scan_p1(
    const int* __restrict__ cnt, int* __restrict__ start, int* __restrict__ bsum)
{
    __shared__ int sh[1024];
    int tid = threadIdx.x;
    int i = blockIdx.x * 1024 + tid;
    int v = (i < NSEG) ? cnt[i] : 0;
    sh[tid] = v;
    __syncthreads();
    for (int off = 1; off < 1024; off <<= 1) {
        int t = (tid >= off) ? sh[tid - off] : 0;
        __syncthreads();
        sh[tid] += t;
        __syncthreads();
    }
    if (i < NSEG) start[i] = sh[tid] - v;
    if (tid == 1023) bsum[blockIdx.x] = sh[1023];
}

// Scan P2: exclusive scan of block totals (single block)
__global__ __launch_bounds__(128) void scan_p2(int* __restrict__ bsum)
{
    __shared__ int sh[128];
    int tid = threadIdx.x;
    int v = (tid < NB1) ? bsum[tid] : 0;
    sh[tid] = v;
    __syncthreads();
    for (int off = 1; off < 128; off <<= 1) {
        int t = (tid >= off) ? sh[tid - off] : 0;
        __syncthreads();
        sh[tid] += t;
        __syncthreads();
    }
    if (tid < NB1) bsum[tid] = sh[tid] - v;
}

// Scan P3: add block offsets
__global__ __launch_bounds__(1024) void scan_p3(
    int* __restrict__ start, const int* __restrict__ bsum)
{
    int i = blockIdx.x * 1024 + threadIdx.x;
    if (i < NSEG) start[i] += bsum[blockIdx.x];
}

// Phase C: scatter point ids into segment-ordered list; start[] becomes end[]
__global__ __launch_bounds__(256) void phase_c(
    const int* __restrict__ rank, int* __restrict__ start, int* __restrict__ order)
{
    int p = blockIdx.x * 256 + threadIdx.x;
    if (p >= TOTP) return;
    int seg = rank[p];
    if (seg < 0) return;
    int pos = atomicAdd(&start[seg], 1);
    order[pos] = p;
}

// ---------------------------------------------------------------------------
// Phase D: 32 voxels per 256-thread block (8 per wave). Each point's 64
// channels are read as 16 lanes x float4; subgroup g (lanes g*16..g*16+15)
// walks points t = begin+g, begin+g+4, ... loading order[t] directly (same
// address across the 16 lanes -> HW broadcast; order[] is L1/L2 resident).
// NO cross-lane ops inside the divergent loop. After reconvergence, a
// shfl_xor(16,32) float4 reduce combines the 4 subgroups, then LDS transpose
// and coalesced out[b][c][xy] writes. No atomics.
// ---------------------------------------------------------------------------
__global__ __launch_bounds__(256) void phase_d(
    const int* __restrict__ endp, const int* __restrict__ order,
    const float* __restrict__ x, float* __restrict__ out)
{
    __shared__ float tile[32][68];
    int blk  = blockIdx.x;                 // 0 .. 2499
    int b    = blk / (NVOX/32);            // 1250 blocks per batch
    int xy0  = (blk % (NVOX/32)) * 32;
    int wv   = threadIdx.x >> 6;           // 0..3
    int lane = threadIdx.x & 63;
    int seg0 = b * NVOX + xy0 + wv * 8;    // this wave's first voxel

    // lane j<9 loads boundary end[seg0-1+j]; e[v]=begin of voxel v, e[v+1]=end
    int e = 0;
    if (lane < 9) {
        int idx = seg0 - 1 + lane;
        e = (idx >= 0) ? endp[idx] : 0;
    }

    int g = lane >> 4;                     // point subgroup 0..3
    int q = (lane & 15) * 4;               // channel base for this lane

    for (int v = 0; v < 8; ++v) {
        int begin = __shfl(e, v);          // wave-uniform
        int endv  = __shfl(e, v + 1);      // wave-uniform
        float4 sum = make_float4(0.f, 0.f, 0.f, 0.f);
        for (int t = begin + g; t < endv; t += 4) {
            int p = order[t];              // broadcast within subgroup
            const float4 vv = *(const float4*)(x + (long)p * Cc + q);
            sum.x += vv.x; sum.y += vv.y; sum.z += vv.z; sum.w += vv.w;
        }
        // reconverged: reduce the 4 point-subgroups (lanes l, l^16, l^32, l^48)
        #pragma unroll
        for (int m = 16; m <= 32; m <<= 1) {
            sum.x += __shfl_xor(sum.x, m);
            sum.y += __shfl_xor(sum.y, m);
            sum.z += __shfl_xor(sum.z, m);
            sum.w += __shfl_xor(sum.w, m);
        }
        if (g == 0) *(float4*)&tile[wv*8 + v][q] = sum;
    }
    __syncthreads();

    // out[b][c][xy0+xy]: iteration s writes 8 channels x 32 xy
    float* dst = out + (long)b * Cc * NVOX + xy0;
    int xy = threadIdx.x & 31;
    int c0 = threadIdx.x >> 5;             // 0..7
    #pragma unroll
    for (int s = 0; s < 8; ++s) {
        int c = s * 8 + c0;
        dst[(long)c * NVOX + xy] = tile[xy][c];
    }
}

// ---------------------------------------------------------------------------
// Fallback (r1 atomic path) if ws is unexpectedly small
// ---------------------------------------------------------------------------
__global__ __launch_bounds__(256) void fiery_scatter_direct(
    const float* __restrict__ x, const float* __restrict__ geom,
    float* __restrict__ out)
{
    int wid  = blockIdx.x * 4 + (threadIdx.x >> 6);
    int lane = threadIdx.x & 63;
    if (wid >= TOTP) return;
    long gb = (long)wid * 3;
    float gx = geom[gb+0], gy = geom[gb+1], gz = geom[gb+2];
    int vx = (int)((gx + 50.0f) / 0.5f);
    int vy = (int)((gy + 50.0f) / 0.5f);
    int vz = (int)((gz + 10.0f) / 20.0f);
    if (!(vx >= 0 && vx < Xd && vy >= 0 && vy < Yd && vz == 0)) return;
    int b = (wid >= NP) ? 1 : 0;
    float vv = x[(long)wid * Cc + lane];
    long dst = ((long)(b * Cc + lane)) * NVOX + (vx * Yd + vy);
    atomicAdd(&out[dst], vv);
}

extern "C" void kernel_launch(void* const* d_in, const int* in_sizes, int n_in,
                              void* d_out, int out_size, void* d_ws, size_t ws_size,
                              hipStream_t stream)
{
    const float* x    = (const float*)d_in[0];
    const float* geom = (const float*)d_in[1];
    float* out = (float*)d_out;

    // ws layout: rank[TOTP] | order[TOTP] | cnt[NSEG] | start[NSEG] | bsum[128]
    size_t need = ((size_t)TOTP * 2 + (size_t)NSEG * 2 + 128) * sizeof(int);
    if (ws_size >= need) {
        int* rank  = (int*)d_ws;
        int* order = rank  + TOTP;
        int* cnt   = order + TOTP;
        int* start = cnt   + NSEG;
        int* bsum  = start + NSEG;

        hipMemsetAsync(cnt, 0, (size_t)NSEG * sizeof(int), stream);
        phase_a<<<TOTP/256, 256, 0, stream>>>(geom, rank, cnt);
        scan_p1<<<NB1, 1024, 0, stream>>>(cnt, start, bsum);
        scan_p2<<<1, 128, 0, stream>>>(bsum);
        scan_p3<<<NB1, 1024, 0, stream>>>(start, bsum);
        phase_c<<<TOTP/256, 256, 0, stream>>>(rank, start, order);
        phase_d<<<Bq*(NVOX/32), 256, 0, stream>>>(start, order, x, out);
    } else {
        hipMemsetAsync(out, 0, (size_t)out_size * sizeof(float), stream);
        fiery_scatter_direct<<<TOTP/4, 256, 0, stream>>>(x, geom, out);
    }
}

// Round 5
// 130.345 us; speedup vs baseline: 1.6989x; 1.0330x over previous
//
#include <hip/hip_runtime.h>

#define Bq 2
#define Nn 6
#define Dd 48
#define Hh 28
#define Ww 60
#define Cc 64
#define Xd 200
#define Yd 200
#define NP (Nn*Dd*Hh*Ww)      // 483840 points per batch
#define TOTP (Bq*NP)          // 967680 total points
#define NVOX (Xd*Yd)          // 40000 voxels per batch (Z=1)
#define NSEG (Bq*NVOX)        // 80000 segments
#define NB1  79               // ceil(NSEG/1024)

// Zero the histogram ourselves: rocclr's fillBufferAligned for this small
// memset measured 144 us (!) in the graph; this kernel is ~2 us.
__global__ __launch_bounds__(1024) void zero_cnt(int* __restrict__ cnt)
{
    int i = blockIdx.x * 1024 + threadIdx.x;
    if (i < NSEG) cnt[i] = 0;
}

// ---------------------------------------------------------------------------
// Phase A: voxelize each point, store segment id (-1 invalid), histogram count
// ---------------------------------------------------------------------------
__global__ __launch_bounds__(256) void phase_a(
    const float* __restrict__ geom, int* __restrict__ rank, int* __restrict__ cnt)
{
    int p = blockIdx.x * 256 + threadIdx.x;
    if (p >= TOTP) return;
    float gx = geom[(long)p*3 + 0];
    float gy = geom[(long)p*3 + 1];
    float gz = geom[(long)p*3 + 2];
    // must match numpy astype(int32): truncate toward zero, f32 arithmetic
    int vx = (int)((gx + 50.0f) / 0.5f);
    int vy = (int)((gy + 50.0f) / 0.5f);
    int vz = (int)((gz + 10.0f) / 20.0f);
    int seg = -1;
    if (vx >= 0 && vx < Xd && vy >= 0 && vy < Yd && vz == 0) {
        int b = (p >= NP) ? 1 : 0;
        seg = b * NVOX + vx * Yd + vy;
        atomicAdd(&cnt[seg], 1);
    }
    rank[p] = seg;
}

// Scan P1: per-1024-block exclusive scan of cnt -> start, block totals -> bsum
__global__ __launch_bounds__(1024) void scan_p1(
    const int* __restrict__ cnt, int* __restrict__ start, int* __restrict__ bsum)
{
    __shared__ int sh[1024];
    int tid = threadIdx.x;
    int i = blockIdx.x * 1024 + tid;
    int v = (i < NSEG) ? cnt[i] : 0;
    sh[tid] = v;
    __syncthreads();
    for (int off = 1; off < 1024; off <<= 1) {
        int t = (tid >= off) ? sh[tid - off] : 0;
        __syncthreads();
        sh[tid] += t;
        __syncthreads();
    }
    if (i < NSEG) start[i] = sh[tid] - v;
    if (tid == 1023) bsum[blockIdx.x] = sh[1023];
}

// Scan P2: exclusive scan of block totals (single block)
__global__ __launch_bounds__(128) void scan_p2(int* __restrict__ bsum)
{
    __shared__ int sh[128];
    int tid = threadIdx.x;
    int v = (tid < NB1) ? bsum[tid] : 0;
    sh[tid] = v;
    __syncthreads();
    for (int off = 1; off < 128; off <<= 1) {
        int t = (tid >= off) ? sh[tid - off] : 0;
        __syncthreads();
        sh[tid] += t;
        __syncthreads();
    }
    if (tid < NB1) bsum[tid] = sh[tid] - v;
}

// Scan P3: add block offsets
__global__ __launch_bounds__(1024) void scan_p3(
    int* __restrict__ start, const int* __restrict__ bsum)
{
    int i = blockIdx.x * 1024 + threadIdx.x;
    if (i < NSEG) start[i] += bsum[blockIdx.x];
}

// Phase C: scatter point ids into segment-ordered list; start[] becomes end[]
__global__ __launch_bounds__(256) void phase_c(
    const int* __restrict__ rank, int* __restrict__ start, int* __restrict__ order)
{
    int p = blockIdx.x * 256 + threadIdx.x;
    if (p >= TOTP) return;
    int seg = rank[p];
    if (seg < 0) return;
    int pos = atomicAdd(&start[seg], 1);
    order[pos] = p;
}

// ---------------------------------------------------------------------------
// Phase D: 32 voxels per 256-thread block (8 per wave). Each point's 64
// channels are read as 16 lanes x float4; subgroup g walks points
// t = begin+g, begin+g+4, ... with a 2-wide manual unroll so two independent
// order[]+x[] load pairs are in flight per chain step. No cross-lane ops in
// the divergent loop; shfl_xor(16,32) reduce after reconvergence; LDS
// transpose; coalesced out[b][c][xy] writes. No atomics.
// ---------------------------------------------------------------------------
__global__ __launch_bounds__(256) void phase_d(
    const int* __restrict__ endp, const int* __restrict__ order,
    const float* __restrict__ x, float* __restrict__ out)
{
    __shared__ float tile[32][68];
    int blk  = blockIdx.x;                 // 0 .. 2499
    int b    = blk / (NVOX/32);            // 1250 blocks per batch
    int xy0  = (blk % (NVOX/32)) * 32;
    int wv   = threadIdx.x >> 6;           // 0..3
    int lane = threadIdx.x & 63;
    int seg0 = b * NVOX + xy0 + wv * 8;    // this wave's first voxel

    // lane j<9 loads boundary end[seg0-1+j]; e[v]=begin of voxel v, e[v+1]=end
    int e = 0;
    if (lane < 9) {
        int idx = seg0 - 1 + lane;
        e = (idx >= 0) ? endp[idx] : 0;
    }

    int g = lane >> 4;                     // point subgroup 0..3
    int q = (lane & 15) * 4;               // channel base for this lane

    for (int v = 0; v < 8; ++v) {
        int begin = __shfl(e, v);          // wave-uniform
        int endv  = __shfl(e, v + 1);      // wave-uniform
        float4 sum = make_float4(0.f, 0.f, 0.f, 0.f);
        int t = begin + g;
        for (; t + 4 < endv; t += 8) {     // 2 points per chain step
            int p0 = order[t];
            int p1 = order[t + 4];
            const float4 a0 = *(const float4*)(x + (long)p0 * Cc + q);
            const float4 a1 = *(const float4*)(x + (long)p1 * Cc + q);
            sum.x += a0.x + a1.x; sum.y += a0.y + a1.y;
            sum.z += a0.z + a1.z; sum.w += a0.w + a1.w;
        }
        if (t < endv) {
            int p0 = order[t];
            const float4 a0 = *(const float4*)(x + (long)p0 * Cc + q);
            sum.x += a0.x; sum.y += a0.y; sum.z += a0.z; sum.w += a0.w;
        }
        // reconverged: reduce the 4 point-subgroups (lanes l, l^16, l^32, l^48)
        #pragma unroll
        for (int m = 16; m <= 32; m <<= 1) {
            sum.x += __shfl_xor(sum.x, m);
            sum.y += __shfl_xor(sum.y, m);
            sum.z += __shfl_xor(sum.z, m);
            sum.w += __shfl_xor(sum.w, m);
        }
        if (g == 0) *(float4*)&tile[wv*8 + v][q] = sum;
    }
    __syncthreads();

    // out[b][c][xy0+xy]: iteration s writes 8 channels x 32 xy
    float* dst = out + (long)b * Cc * NVOX + xy0;
    int xy = threadIdx.x & 31;
    int c0 = threadIdx.x >> 5;             // 0..7
    #pragma unroll
    for (int s = 0; s < 8; ++s) {
        int c = s * 8 + c0;
        dst[(long)c * NVOX + xy] = tile[xy][c];
    }
}

// ---------------------------------------------------------------------------
// Fallback (r1 atomic path) if ws is unexpectedly small
// ---------------------------------------------------------------------------
__global__ __launch_bounds__(256) void fiery_scatter_direct(
    const float* __restrict__ x, const float* __restrict__ geom,
    float* __restrict__ out)
{
    int wid  = blockIdx.x * 4 + (threadIdx.x >> 6);
    int lane = threadIdx.x & 63;
    if (wid >= TOTP) return;
    long gb = (long)wid * 3;
    float gx = geom[gb+0], gy = geom[gb+1], gz = geom[gb+2];
    int vx = (int)((gx + 50.0f) / 0.5f);
    int vy = (int)((gy + 50.0f) / 0.5f);
    int vz = (int)((gz + 10.0f) / 20.0f);
    if (!(vx >= 0 && vx < Xd && vy >= 0 && vy < Yd && vz == 0)) return;
    int b = (wid >= NP) ? 1 : 0;
    float vv = x[(long)wid * Cc + lane];
    long dst = ((long)(b * Cc + lane)) * NVOX + (vx * Yd + vy);
    atomicAdd(&out[dst], vv);
}

extern "C" void kernel_launch(void* const* d_in, const int* in_sizes, int n_in,
                              void* d_out, int out_size, void* d_ws, size_t ws_size,
                              hipStream_t stream)
{
    const float* x    = (const float*)d_in[0];
    const float* geom = (const float*)d_in[1];
    float* out = (float*)d_out;

    // ws layout: rank[TOTP] | order[TOTP] | cnt[NSEG] | start[NSEG] | bsum[128]
    size_t need = ((size_t)TOTP * 2 + (size_t)NSEG * 2 + 128) * sizeof(int);
    if (ws_size >= need) {
        int* rank  = (int*)d_ws;
        int* order = rank  + TOTP;
        int* cnt   = order + TOTP;
        int* start = cnt   + NSEG;
        int* bsum  = start + NSEG;

        zero_cnt<<<NB1, 1024, 0, stream>>>(cnt);
        phase_a<<<TOTP/256, 256, 0, stream>>>(geom, rank, cnt);
        scan_p1<<<NB1, 1024, 0, stream>>>(cnt, start, bsum);
        scan_p2<<<1, 128, 0, stream>>>(bsum);
        scan_p3<<<NB1, 1024, 0, stream>>>(start, bsum);
        phase_c<<<TOTP/256, 256, 0, stream>>>(rank, start, order);
        phase_d<<<Bq*(NVOX/32), 256, 0, stream>>>(start, order, x, out);
    } else {
        hipMemsetAsync(out, 0, (size_t)out_size * sizeof(float), stream);
        fiery_scatter_direct<<<TOTP/4, 256, 0, stream>>>(x, geom, out);
    }
}

// Round 6
// 124.324 us; speedup vs baseline: 1.7812x; 1.0484x over previous
//
#include <hip/hip_runtime.h>

#define Bq 2
#define Nn 6
#define Dd 48
#define Hh 28
#define Ww 60
#define Cc 64
#define Xd 200
#define Yd 200
#define NP (Nn*Dd*Hh*Ww)      // 483840 points per batch
#define TOTP (Bq*NP)          // 967680 total points
#define NVOX (Xd*Yd)          // 40000 voxels per batch (Z=1)
#define NSEG (Bq*NVOX)        // 80000 segments
#define NB1  79               // ceil(NSEG/1024)
#define CAP  512              // staged point-ids per wave (avg need ~67)

// Zero the histogram ourselves: rocclr fillBufferAligned is pathologically slow
__global__ __launch_bounds__(1024) void zero_cnt(int* __restrict__ cnt)
{
    int i = blockIdx.x * 1024 + threadIdx.x;
    if (i < NSEG) cnt[i] = 0;
}

// ---------------------------------------------------------------------------
// Phase A: voxelize each point, store segment id (-1 invalid), histogram count
// ---------------------------------------------------------------------------
__global__ __launch_bounds__(256) void phase_a(
    const float* __restrict__ geom, int* __restrict__ rank, int* __restrict__ cnt)
{
    int p = blockIdx.x * 256 + threadIdx.x;
    if (p >= TOTP) return;
    float gx = geom[(long)p*3 + 0];
    float gy = geom[(long)p*3 + 1];
    float gz = geom[(long)p*3 + 2];
    // must match numpy astype(int32): truncate toward zero, f32 arithmetic
    int vx = (int)((gx + 50.0f) / 0.5f);
    int vy = (int)((gy + 50.0f) / 0.5f);
    int vz = (int)((gz + 10.0f) / 20.0f);
    int seg = -1;
    if (vx >= 0 && vx < Xd && vy >= 0 && vy < Yd && vz == 0) {
        int b = (p >= NP) ? 1 : 0;
        seg = b * NVOX + vx * Yd + vy;
        atomicAdd(&cnt[seg], 1);
    }
    rank[p] = seg;
}

// Scan P1: per-1024-block exclusive scan of cnt -> start, block totals -> bsum
__global__ __launch_bounds__(1024) void scan_p1(
    const int* __restrict__ cnt, int* __restrict__ start, int* __restrict__ bsum)
{
    __shared__ int sh[1024];
    int tid = threadIdx.x;
    int i = blockIdx.x * 1024 + tid;
    int v = (i < NSEG) ? cnt[i] : 0;
    sh[tid] = v;
    __syncthreads();
    for (int off = 1; off < 1024; off <<= 1) {
        int t = (tid >= off) ? sh[tid - off] : 0;
        __syncthreads();
        sh[tid] += t;
        __syncthreads();
    }
    if (i < NSEG) start[i] = sh[tid] - v;
    if (tid == 1023) bsum[blockIdx.x] = sh[1023];
}

// Scan P2: exclusive scan of block totals (single block)
__global__ __launch_bounds__(128) void scan_p2(int* __restrict__ bsum)
{
    __shared__ int sh[128];
    int tid = threadIdx.x;
    int v = (tid < NB1) ? bsum[tid] : 0;
    sh[tid] = v;
    __syncthreads();
    for (int off = 1; off < 128; off <<= 1) {
        int t = (tid >= off) ? sh[tid - off] : 0;
        __syncthreads();
        sh[tid] += t;
        __syncthreads();
    }
    if (tid < NB1) bsum[tid] = sh[tid] - v;
}

// Scan P3: add block offsets
__global__ __launch_bounds__(1024) void scan_p3(
    int* __restrict__ start, const int* __restrict__ bsum)
{
    int i = blockIdx.x * 1024 + threadIdx.x;
    if (i < NSEG) start[i] += bsum[blockIdx.x];
}

// Phase C: scatter point ids into segment-ordered list; start[] becomes end[]
__global__ __launch_bounds__(256) void phase_c(
    const int* __restrict__ rank, int* __restrict__ start, int* __restrict__ order)
{
    int p = blockIdx.x * 256 + threadIdx.x;
    if (p >= TOTP) return;
    int seg = rank[p];
    if (seg < 0) return;
    int pos = atomicAdd(&start[seg], 1);
    order[pos] = p;
}

// ---------------------------------------------------------------------------
// Phase D: 32 voxels per block (8/wave). The wave's 8 voxels own a CONTIGUOUS
// slice of order[] (e[0]..e[8]); stage those ids into LDS with 1-2 coalesced
// loads, then the inner gather's chain is LDS-read -> x float4 load (one
// global round per step instead of two). 16 lanes x float4 per point, 4
// point-subgroups, shfl_xor(16,32) reduce after reconvergence, LDS transpose,
// coalesced out[b][c][xy] writes. No atomics.
// ---------------------------------------------------------------------------
__global__ __launch_bounds__(256) void phase_d(
    const int* __restrict__ endp, const int* __restrict__ order,
    const float* __restrict__ x, float* __restrict__ out)
{
    __shared__ int   ord_sh[4][CAP];
    __shared__ float tile[32][68];
    int blk  = blockIdx.x;                 // 0 .. 2499
    int b    = blk / (NVOX/32);            // 1250 blocks per batch
    int xy0  = (blk % (NVOX/32)) * 32;
    int wv   = threadIdx.x >> 6;           // 0..3
    int lane = threadIdx.x & 63;
    int seg0 = b * NVOX + xy0 + wv * 8;    // this wave's first voxel

    // lane j<9 loads boundary end[seg0-1+j]; e[v]=begin of voxel v, e[v+1]=end
    int e = 0;
    if (lane < 9) {
        int idx = seg0 - 1 + lane;
        e = (idx >= 0) ? endp[idx] : 0;
    }
    int e0 = __shfl(e, 0);                 // wave-uniform begin
    int e8 = __shfl(e, 8);                 // wave-uniform end
    int count = e8 - e0;

    int g = lane >> 4;                     // point subgroup 0..3
    int q = (lane & 15) * 4;               // channel base for this lane

    if (count <= CAP) {                    // ~always (avg 67, ~10-sigma margin)
        for (int i = lane; i < count; i += 64)
            ord_sh[wv][i] = order[e0 + i]; // coalesced; wave-private region
        for (int v = 0; v < 8; ++v) {
            int rb = __shfl(e, v)     - e0;
            int re = __shfl(e, v + 1) - e0;
            float4 sum = make_float4(0.f, 0.f, 0.f, 0.f);
            int t = rb + g;
            for (; t + 4 < re; t += 8) {   // 2 points per chain step
                int p0 = ord_sh[wv][t];
                int p1 = ord_sh[wv][t + 4];
                const float4 a0 = *(const float4*)(x + (long)p0 * Cc + q);
                const float4 a1 = *(const float4*)(x + (long)p1 * Cc + q);
                sum.x += a0.x + a1.x; sum.y += a0.y + a1.y;
                sum.z += a0.z + a1.z; sum.w += a0.w + a1.w;
            }
            if (t < re) {
                int p0 = ord_sh[wv][t];
                const float4 a0 = *(const float4*)(x + (long)p0 * Cc + q);
                sum.x += a0.x; sum.y += a0.y; sum.z += a0.z; sum.w += a0.w;
            }
            #pragma unroll
            for (int m = 16; m <= 32; m <<= 1) {
                sum.x += __shfl_xor(sum.x, m);
                sum.y += __shfl_xor(sum.y, m);
                sum.z += __shfl_xor(sum.z, m);
                sum.w += __shfl_xor(sum.w, m);
            }
            if (g == 0) *(float4*)&tile[wv*8 + v][q] = sum;
        }
    } else {                               // fallback: direct global order[]
        for (int v = 0; v < 8; ++v) {
            int begin = __shfl(e, v);
            int endv  = __shfl(e, v + 1);
            float4 sum = make_float4(0.f, 0.f, 0.f, 0.f);
            for (int t = begin + g; t < endv; t += 4) {
                int p0 = order[t];
                const float4 a0 = *(const float4*)(x + (long)p0 * Cc + q);
                sum.x += a0.x; sum.y += a0.y; sum.z += a0.z; sum.w += a0.w;
            }
            #pragma unroll
            for (int m = 16; m <= 32; m <<= 1) {
                sum.x += __shfl_xor(sum.x, m);
                sum.y += __shfl_xor(sum.y, m);
                sum.z += __shfl_xor(sum.z, m);
                sum.w += __shfl_xor(sum.w, m);
            }
            if (g == 0) *(float4*)&tile[wv*8 + v][q] = sum;
        }
    }
    __syncthreads();

    // out[b][c][xy0+xy]: iteration s writes 8 channels x 32 xy
    float* dst = out + (long)b * Cc * NVOX + xy0;
    int xy = threadIdx.x & 31;
    int c0 = threadIdx.x >> 5;             // 0..7
    #pragma unroll
    for (int s = 0; s < 8; ++s) {
        int c = s * 8 + c0;
        dst[(long)c * NVOX + xy] = tile[xy][c];
    }
}

// ---------------------------------------------------------------------------
// Fallback (r1 atomic path) if ws is unexpectedly small
// ---------------------------------------------------------------------------
__global__ __launch_bounds__(256) void fiery_scatter_direct(
    const float* __restrict__ x, const float* __restrict__ geom,
    float* __restrict__ out)
{
    int wid  = blockIdx.x * 4 + (threadIdx.x >> 6);
    int lane = threadIdx.x & 63;
    if (wid >= TOTP) return;
    long gb = (long)wid * 3;
    float gx = geom[gb+0], gy = geom[gb+1], gz = geom[gb+2];
    int vx = (int)((gx + 50.0f) / 0.5f);
    int vy = (int)((gy + 50.0f) / 0.5f);
    int vz = (int)((gz + 10.0f) / 20.0f);
    if (!(vx >= 0 && vx < Xd && vy >= 0 && vy < Yd && vz == 0)) return;
    int b = (wid >= NP) ? 1 : 0;
    float vv = x[(long)wid * Cc + lane];
    long dst = ((long)(b * Cc + lane)) * NVOX + (vx * Yd + vy);
    atomicAdd(&out[dst], vv);
}

extern "C" void kernel_launch(void* const* d_in, const int* in_sizes, int n_in,
                              void* d_out, int out_size, void* d_ws, size_t ws_size,
                              hipStream_t stream)
{
    const float* x    = (const float*)d_in[0];
    const float* geom = (const float*)d_in[1];
    float* out = (float*)d_out;

    // ws layout: rank[TOTP] | order[TOTP] | cnt[NSEG] | start[NSEG] | bsum[128]
    size_t need = ((size_t)TOTP * 2 + (size_t)NSEG * 2 + 128) * sizeof(int);
    if (ws_size >= need) {
        int* rank  = (int*)d_ws;
        int* order = rank  + TOTP;
        int* cnt   = order + TOTP;
        int* start = cnt   + NSEG;
        int* bsum  = start + NSEG;

        zero_cnt<<<NB1, 1024, 0, stream>>>(cnt);
        phase_a<<<TOTP/256, 256, 0, stream>>>(geom, rank, cnt);
        scan_p1<<<NB1, 1024, 0, stream>>>(cnt, start, bsum);
        scan_p2<<<1, 128, 0, stream>>>(bsum);
        scan_p3<<<NB1, 1024, 0, stream>>>(start, bsum);
        phase_c<<<TOTP/256, 256, 0, stream>>>(rank, start, order);
        phase_d<<<Bq*(NVOX/32), 256, 0, stream>>>(start, order, x, out);
    } else {
        hipMemsetAsync(out, 0, (size_t)out_size * sizeof(float), stream);
        fiery_scatter_direct<<<TOTP/4, 256, 0, stream>>>(x, geom, out);
    }
}